// Round 9
// baseline (267.358 us; speedup 1.0000x reference)
//
#include <hip/hip_runtime.h>
#include <hip/hip_bf16.h>
#include <math.h>

// Problem constants (B, NA, NO, D, C, T) = (2048, 64, 64, 128, 64, 3)
#define NB 2048
#define NNODES 129
#define ND 128
#define NC 64
#define BPB 2
#define NBLK (NB / BPB)   // 1024 blocks = exactly 4 blocks/CU x 256 CU, co-resident

typedef unsigned int u32;

// ws float layout:
//  [0]              : mask-dtype flag (int)
//  [16 .. 16+1152)  : u[j*3+i][d]  (9 x 128)   u = W[j] @ a1[i]
//  [1168 .. +384)   : v2[i][d]     (3 x 128)   v2 = W[i] @ a2[i]

__device__ __forceinline__ bool mask_at(const void* m, int flag, int idx) {
  if (flag == 1) return ((const unsigned char*)m)[idx] != 0;
  if (flag == 2) return ((const float*)m)[idx] != 0.0f;
  return ((const int*)m)[idx] != 0;
}

__device__ __forceinline__ u32 pack2bf(float a, float b) {
  __hip_bfloat162 p = __float22bfloat162_rn(make_float2(a, b));  // v_cvt_pk_bf16_f32
  u32 w;
  __builtin_memcpy(&w, &p, 4);
  return w;
}
__device__ __forceinline__ float2 unpack2bf(u32 w) {
  float lo = __builtin_bit_cast(float, w << 16);
  float hi = __builtin_bit_cast(float, w & 0xffff0000u);
  return make_float2(lo, hi);
}
__device__ __forceinline__ float dot4(float4 a, float4 b) {
  return a.x * b.x + a.y * b.y + a.z * b.z + a.w * b.w;
}

__global__ void hetgat_precomp(const float* __restrict__ W, const float* __restrict__ a,
                               const void* __restrict__ mask, float* __restrict__ ws) {
  int gidx = blockIdx.x * 256 + threadIdx.x;
  if (blockIdx.x == 6) {
    if (threadIdx.x == 0) {
      const unsigned char* mb = (const unsigned char*)mask;
      const unsigned int* mw = (const unsigned int*)mask;
      bool bytes01 = true, words01 = true, wordsF = true;
      for (int i = 0; i < 256; ++i) { if (mb[i] > 1) bytes01 = false; }
      for (int i = 0; i < 64; ++i) {
        unsigned int w = mw[i];
        if (w != 0u && w != 1u) words01 = false;
        if (w != 0u && w != 0x3F800000u) wordsF = false;
      }
      int flag;
      if (words01) flag = 0;
      else if (bytes01) flag = 1;
      else if (wordsF) flag = 2;
      else flag = 1;
      ((int*)ws)[0] = flag;
    }
    return;
  }
  if (gidx < 1152) {                // u[j*3+i][d]
    int ji = gidx >> 7, d = gidx & 127;
    int j = ji / 3, i = ji - 3 * j;
    const float4* Wp = (const float4*)(W + j * 8192 + d * 64);
    const float4* ap = (const float4*)(a + i * 128);
    float s = 0.f;
#pragma unroll
    for (int c = 0; c < 16; ++c) {
      float4 w4 = Wp[c], a4 = ap[c];
      s += w4.x * a4.x + w4.y * a4.y + w4.z * a4.z + w4.w * a4.w;
    }
    ws[16 + gidx] = s;
  } else if (gidx < 1536) {         // v2[i][d]
    int rel = gidx - 1152;
    int i = rel >> 7, d = rel & 127;
    const float4* Wp = (const float4*)(W + i * 8192 + d * 64);
    const float4* ap = (const float4*)(a + i * 128 + 64);
    float s = 0.f;
#pragma unroll
    for (int c = 0; c < 16; ++c) {
      float4 w4 = Wp[c], a4 = ap[c];
      s += w4.x * a4.x + w4.y * a4.y + w4.z * a4.z + w4.w * a4.w;
    }
    ws[1168 + rel] = s;
  }
}

// LDS float offsets (all float4 regions 16B-aligned).
// hl: rows 1..128 as bf16x2, 64 u32/row, 16B-chunk swizzle: chunk ^= row&7.
#define OFF_HL   0        // 8192 (u32)
#define OFF_W2   8192     // 384 = w2[3][128] (n<64 ally, n>=64 opp)
#define OFF_ERA  8576     // 192
#define OFF_ERO  8768     // 192
#define OFF_GL   8960     // 384
#define OFF_V2L  9344     // 384
#define OFF_RED  9728     // 256
#define OFF_ESW  9984     // 18 (2 waves x 9)
#define OFF_MSF  10002    // 3
#define LDS_FLOATS 10005  // 40,020 B -> 4 blocks/CU

__device__ __forceinline__ void load_masks(const void* mask, int flag, int b,
                                           int wv, int ln,
                                           bool& m0, bool& m1, bool& m2, float& ms) {
  if (wv == 0) {
    int base = b * NNODES + 1 + ln;
    m0 = mask_at(mask, flag, base);
    m1 = mask_at(mask, flag, NB * NNODES + base);
    m2 = mask_at(mask, flag, 2 * NB * NNODES + base);
  } else if (wv == 1) {
    int base = b * NNODES + 65 + ln;
    m0 = mask_at(mask, flag, base);
    m1 = mask_at(mask, flag, NB * NNODES + base);
    m2 = mask_at(mask, flag, 2 * NB * NNODES + base);
  } else if (wv == 2 && ln < 3) {
    ms = mask_at(mask, flag, (ln * NB + b) * NNODES) ? 1.f : 0.f;
  }
}

// logits from f32 registers + pack own half-row into swizzled bf16 LDS
__device__ __forceinline__ void logits_pack(u32* hl, float* era, float* ero,
                                            const float* v2l,
                                            const float4 (&hreg)[16], int tid) {
  const int half = tid & 1;
  const int row = (tid >> 1) + 1;          // 1..128
  float a0 = 0.f, a1 = 0.f, a2 = 0.f;
  const float4* vv = (const float4*)v2l + half * 16;
#pragma unroll
  for (int q = 0; q < 16; ++q) {
    float4 x = hreg[q];
    a0 += dot4(x, vv[q]);
    a1 += dot4(x, vv[32 + q]);
    a2 += dot4(x, vv[64 + q]);
  }
  const int s = row & 7;
#pragma unroll
  for (int k = 0; k < 8; ++k) {            // 8 uint4 chunks of own half-row
    float4 u = hreg[2 * k], v = hreg[2 * k + 1];
    uint4 w;
    w.x = pack2bf(u.x, u.y); w.y = pack2bf(u.z, u.w);
    w.z = pack2bf(v.x, v.y); w.w = pack2bf(v.z, v.w);
    *(uint4*)(hl + (row - 1) * 64 + (((half * 8 + k) ^ s) << 2)) = w;
  }
  a0 += __shfl_xor(a0, 1);
  a1 += __shfl_xor(a1, 1);
  a2 += __shfl_xor(a2, 1);
  if (half == 0) {
    if (row <= 64) {
      era[row - 1] = a0; era[64 + row - 1] = a1; era[128 + row - 1] = a2;
    } else {
      ero[row - 65] = a0; ero[64 + row - 65] = a1; ero[128 + row - 65] = a2;
    }
  }
}

__global__ __launch_bounds__(256, 4) void hetgat_main(
    const float* __restrict__ h, const float* __restrict__ W,
    const void* __restrict__ mask, const float* __restrict__ ws,
    float* __restrict__ out) {
  __shared__ float lds[LDS_FLOATS];
  u32* hl    = (u32*)lds;
  float* w2  = lds + OFF_W2;
  float* era = lds + OFF_ERA;
  float* ero = lds + OFF_ERO;
  float* gl  = lds + OFF_GL;
  float* v2l = lds + OFF_V2L;
  float* red = lds + OFF_RED;
  float* esw = lds + OFF_ESW;
  float* msf = lds + OFF_MSF;

  const int tid = threadIdx.x;
  const int wv = tid >> 6, ln = tid & 63;
  const int half = tid & 1;
  const int row = (tid >> 1) + 1;
  const int flag = ((const int*)ws)[0];
  const int b0 = blockIdx.x * BPB;

  // ---- prologue ----
  if (tid < 96) ((float4*)v2l)[tid] = ((const float4*)(ws + 1168))[tid];
  float4 hreg[16];
  float r0n = 0.f;   // waves 2,3: h[b][0][tid-128] (self row element)
  {
    const float* hb = h + (size_t)b0 * NNODES * ND;
    const float4* hp = (const float4*)(hb + row * ND + half * 64);
#pragma unroll
    for (int q = 0; q < 16; ++q) hreg[q] = hp[q];
    if (wv >= 2) r0n = hb[tid - 128];
  }
  bool mc0 = false, mc1 = false, mc2 = false; float msc = 0.f;
  load_masks(mask, flag, b0, wv, ln, mc0, mc1, mc2, msc);
  __syncthreads();                         // v2l ready
  logits_pack(hl, era, ero, v2l, hreg, tid);
  if (wv == 2 && ln < 3) msf[ln] = msc;
  __syncthreads();                         // hl/era/ero/msf (b0) ready

  for (int j = 0; j < BPB; ++j) {
    const int b = b0 + j;
    bool mn0 = false, mn1 = false, mn2 = false; float msn = 0.f;
    float r0next = 0.f;

    // [1] issue next-b loads (hidden under phases below)
    if (j < BPB - 1) {
      const float* hb = h + (size_t)(b + 1) * NNODES * ND;
      const float4* hp = (const float4*)(hb + row * ND + half * 64);
#pragma unroll
      for (int q = 0; q < 16; ++q) hreg[q] = hp[q];
      if (wv >= 2) r0next = hb[tid - 128];
      load_masks(mask, flag, b + 1, wv, ln, mn0, mn1, mn2, msn);
    }

    // [2] waves 0,1: e_self + collapsed softmax -> w2 ; waves 2,3: gl = self-term
    if (wv < 2) {
      if (ln < 9) {                        // es[j*3+i] = h_self . u[j,i] (f32, global)
        const float4* uu = (const float4*)(ws + 16) + ln * 32;
        const float4* h0 = (const float4*)(h + (size_t)b * NNODES * ND);
        float s = 0.f;
#pragma unroll 8
        for (int ch = 0; ch < 32; ++ch) s += dot4(h0[ch], uu[ch]);
        esw[wv * 9 + ln] = s;
      }
      const float* e = (wv == 0) ? era : ero;
      const float* es = esw + wv * 9;
      float ms3[3], S[3];
#pragma unroll
      for (int i = 0; i < 3; ++i) {
        float e0 = es[i], e1 = es[3 + i], e2 = es[6 + i];
        float m = fmaxf(fmaxf(e0, e1), e2);
        ms3[i] = m;
        S[i] = __expf(e0 - m) + __expf(e1 - m) + __expf(e2 - m);
      }
      float v0  = mc0 ? -INFINITY : e[ln];
      float v1  = mc1 ? -INFINITY : e[64 + ln];
      float v2v = mc2 ? -INFINITY : e[128 + ln];
      float c0 = v0 + ms3[0], c1 = v1 + ms3[1], c2 = v2v + ms3[2];
      float mx = fmaxf(fmaxf(c0, c1), c2);
      for (int off = 32; off; off >>= 1) mx = fmaxf(mx, __shfl_xor(mx, off));
      float t0 = 0.f, t1 = 0.f, t2 = 0.f;
      if (mx != -INFINITY) {
        t0 = mc0 ? 0.f : S[0] * __expf(c0 - mx);
        t1 = mc1 ? 0.f : S[1] * __expf(c1 - mx);
        t2 = mc2 ? 0.f : S[2] * __expf(c2 - mx);
      }
      float z = t0 + t1 + t2;
      for (int off = 32; off; off >>= 1) z += __shfl_xor(z, off);
      float inv = (z > 0.f) ? 1.f / z : 0.f;
      w2[wv * 64 + ln]       = t0 * inv;
      w2[128 + wv * 64 + ln] = t1 * inv;
      w2[256 + wv * 64 + ln] = t2 * inv;
    } else {
      int d = tid - 128;                   // 0..127 across waves 2,3
      gl[d]       = msf[0] * r0n;
      gl[128 + d] = msf[1] * r0n;
      gl[256 + d] = msf[2] * r0n;
    }
    __syncthreads();

    // [3] phase C: weighted sums, ds_add into gl (all 4 waves, 32 rows each)
    {
      const int c = ln >> 2, rs = ln & 3;  // c: d-chunk 8c..8c+7 ; rs: row % 4
      float acc0[8], acc1[8], acc2[8];
#pragma unroll
      for (int k = 0; k < 8; ++k) { acc0[k] = 0.f; acc1[k] = 0.f; acc2[k] = 0.f; }
#pragma unroll
      for (int g = 0; g < 8; ++g) {
        int r = 1 + wv * 32 + 4 * g + rs;  // rows 1..128
        int n = r - 1;
        uint4 x = *(const uint4*)(hl + (r - 1) * 64 + ((c ^ (r & 7)) << 2));
        float2 f0 = unpack2bf(x.x), f1 = unpack2bf(x.y), f2 = unpack2bf(x.z), f3 = unpack2bf(x.w);
        float w0 = w2[n], w1 = w2[128 + n], wz = w2[256 + n];
        acc0[0] += w0 * f0.x; acc0[1] += w0 * f0.y; acc0[2] += w0 * f1.x; acc0[3] += w0 * f1.y;
        acc0[4] += w0 * f2.x; acc0[5] += w0 * f2.y; acc0[6] += w0 * f3.x; acc0[7] += w0 * f3.y;
        acc1[0] += w1 * f0.x; acc1[1] += w1 * f0.y; acc1[2] += w1 * f1.x; acc1[3] += w1 * f1.y;
        acc1[4] += w1 * f2.x; acc1[5] += w1 * f2.y; acc1[6] += w1 * f3.x; acc1[7] += w1 * f3.y;
        acc2[0] += wz * f0.x; acc2[1] += wz * f0.y; acc2[2] += wz * f1.x; acc2[3] += wz * f1.y;
        acc2[4] += wz * f2.x; acc2[5] += wz * f2.y; acc2[6] += wz * f3.x; acc2[7] += wz * f3.y;
      }
#pragma unroll
      for (int k = 0; k < 8; ++k) {
        acc0[k] += __shfl_xor(acc0[k], 1); acc0[k] += __shfl_xor(acc0[k], 2);
        acc1[k] += __shfl_xor(acc1[k], 1); acc1[k] += __shfl_xor(acc1[k], 2);
        acc2[k] += __shfl_xor(acc2[k], 1); acc2[k] += __shfl_xor(acc2[k], 2);
      }
      if (rs == 0) {
#pragma unroll
        for (int k = 0; k < 8; ++k) {
          atomicAdd(&gl[8 * c + k],       acc0[k]);
          atomicAdd(&gl[128 + 8 * c + k], acc1[k]);
          atomicAdd(&gl[256 + 8 * c + k], acc2[k]);
        }
      }
    }
    __syncthreads();

    // [5] epilogue partials (all waves) + next-b logits/pack (overlapped)
    {
      int q = wv, cc = ln;
      float acc = 0.f;
#pragma unroll
      for (int t = 0; t < 3; ++t) {
        const float* Wp = W + t * 8192 + cc;
        const float4* g4 = (const float4*)(gl + t * 128) + q * 8;
#pragma unroll
        for (int k = 0; k < 8; ++k) {
          float4 gv = g4[k];
          int dd = q * 32 + k * 4;
          acc += gv.x * Wp[dd * 64] + gv.y * Wp[(dd + 1) * 64]
               + gv.z * Wp[(dd + 2) * 64] + gv.w * Wp[(dd + 3) * 64];
        }
      }
      red[q * 64 + cc] = acc;
    }
    if (j < BPB - 1) {
      logits_pack(hl, era, ero, v2l, hreg, tid);    // waits on [1] loads here
      if (wv == 2 && ln < 3) msf[ln] = msn;
      mc0 = mn0; mc1 = mn1; mc2 = mn2; r0n = r0next;
    }
    __syncthreads();

    // [6] out(b)  (concurrent-safe with next iteration's [2])
    if (tid < 64) {
      float x = red[tid] + red[64 + tid] + red[128 + tid] + red[192 + tid];
      out[(size_t)b * NC + tid] = (x > 0.f) ? x : expm1f(x);
    }
  }
}

extern "C" void kernel_launch(void* const* d_in, const int* in_sizes, int n_in,
                              void* d_out, int out_size, void* d_ws, size_t ws_size,
                              hipStream_t stream) {
  (void)in_sizes; (void)n_in; (void)out_size; (void)ws_size;
  const float* h   = (const float*)d_in[0];
  const float* W   = (const float*)d_in[1];
  const float* a   = (const float*)d_in[2];
  const void* mask = d_in[3];
  float* ws  = (float*)d_ws;
  float* out = (float*)d_out;

  hetgat_precomp<<<dim3(7), dim3(256), 0, stream>>>(W, a, mask, ws);
  hetgat_main<<<dim3(NBLK), dim3(256), 0, stream>>>(h, W, mask, ws, out);
}

// Round 10
// 47.527 us; speedup vs baseline: 5.6254x; 5.6254x over previous
//
#include <hip/hip_runtime.h>
#include <hip/hip_bf16.h>
#include <math.h>

// Problem constants (B, NA, NO, D, C, T) = (2048, 64, 64, 128, 64, 3)
#define NB 2048
#define NNODES 129
#define ND 128
#define NC 64

typedef unsigned int u32;

// ws float layout:
//  [0]              : mask-dtype flag (int): 0=int32, 1=bytes(bool/int8), 2=float32
//  [16 .. 16+1152)  : u[j*3+i][d]  (9 x 128)   u = W[j] @ a1[i]
//  [1168 .. +384)   : v2[i][d]     (3 x 128)   v2 = W[i] @ a2[i]

__device__ __forceinline__ bool mask_at(const void* m, int flag, int idx) {
  if (flag == 1) return ((const unsigned char*)m)[idx] != 0;
  if (flag == 2) return ((const float*)m)[idx] != 0.0f;
  return ((const int*)m)[idx] != 0;
}

__device__ __forceinline__ u32 pack2bf(float a, float b) {
  __hip_bfloat162 p = __float22bfloat162_rn(make_float2(a, b));  // v_cvt_pk_bf16_f32
  u32 w;
  __builtin_memcpy(&w, &p, 4);
  return w;
}
__device__ __forceinline__ float2 unpack2bf(u32 w) {
  float lo = __builtin_bit_cast(float, w << 16);
  float hi = __builtin_bit_cast(float, w & 0xffff0000u);
  return make_float2(lo, hi);
}

__global__ void hetgat_precomp(const float* __restrict__ W, const float* __restrict__ a,
                               const void* __restrict__ mask, float* __restrict__ ws) {
  int gidx = blockIdx.x * 256 + threadIdx.x;
  if (blockIdx.x == 6) {
    if (threadIdx.x == 0) {
      const unsigned char* mb = (const unsigned char*)mask;
      const unsigned int* mw = (const unsigned int*)mask;
      bool bytes01 = true, words01 = true, wordsF = true;
      for (int i = 0; i < 256; ++i) { if (mb[i] > 1) bytes01 = false; }
      for (int i = 0; i < 64; ++i) {
        unsigned int w = mw[i];
        if (w != 0u && w != 1u) words01 = false;
        if (w != 0u && w != 0x3F800000u) wordsF = false;
      }
      int flag;
      if (words01) flag = 0;
      else if (bytes01) flag = 1;
      else if (wordsF) flag = 2;
      else flag = 1;
      ((int*)ws)[0] = flag;
    }
    return;
  }
  if (gidx < 1152) {                // u[j*3+i][d] = sum_c W[j,d,c] * a1[i,c]
    int ji = gidx >> 7, d = gidx & 127;
    int j = ji / 3, i = ji - 3 * j;
    const float4* Wp = (const float4*)(W + j * 8192 + d * 64);
    const float4* ap = (const float4*)(a + i * 128);
    float s = 0.f;
#pragma unroll
    for (int c = 0; c < 16; ++c) {
      float4 w4 = Wp[c], a4 = ap[c];
      s += w4.x * a4.x + w4.y * a4.y + w4.z * a4.z + w4.w * a4.w;
    }
    ws[16 + gidx] = s;
  } else if (gidx < 1536) {         // v2[i][d] = sum_c W[i,d,c] * a2[i,c]
    int rel = gidx - 1152;
    int i = rel >> 7, d = rel & 127;
    const float4* Wp = (const float4*)(W + i * 8192 + d * 64);
    const float4* ap = (const float4*)(a + i * 128 + 64);
    float s = 0.f;
#pragma unroll
    for (int c = 0; c < 16; ++c) {
      float4 w4 = Wp[c], a4 = ap[c];
      s += w4.x * a4.x + w4.y * a4.y + w4.z * a4.z + w4.w * a4.w;
    }
    ws[1168 + rel] = s;
  }
}

// h staged in LDS as bf16, row stride 68 u32 (64 data u32 + 2 pad u32, 16B aligned)
#define ROWU 68
// LDS float/u32 offsets
#define OFF_HL   0                    // 129*68 = 8772 u32
#define OFF_V2L  8772                 // 384 f32 (aliased as red later)
#define OFF_ES   9156                 // 12
#define OFF_EA   9168                 // 192  (ea+eo aliased as gl later)
#define OFF_EO   9360                 // 192
#define OFF_WA   9552                 // 192
#define OFF_WO   9744                 // 192
#define OFF_MSF  9936                 // 4
#define LDS_FLOATS 9940               // 39,760 B -> 4 blocks/CU

__global__ __launch_bounds__(256) void hetgat_main(
    const float* __restrict__ h, const float* __restrict__ W,
    const void* __restrict__ mask, const float* __restrict__ ws,
    float* __restrict__ out) {
  __shared__ float lds[LDS_FLOATS];
  unsigned* hlu = (unsigned*)lds;           // bf16x2 words
  float* v2l = lds + OFF_V2L;
  float* es  = lds + OFF_ES;
  float* ea  = lds + OFF_EA;
  float* eo  = lds + OFF_EO;
  float* wa  = lds + OFF_WA;
  float* wo  = lds + OFF_WO;
  float* msf = lds + OFF_MSF;
  float* gl  = lds + OFF_EA;                // alias (pass3+)
  float* red = lds + OFF_V2L;               // alias (epilogue)

  const int b = blockIdx.x;
  const int tid = threadIdx.x;
  const int wv = tid >> 6;
  const int ln = tid & 63;
  const int flag = ((const int*)ws)[0];

  // ---- entry: prefetch masks into registers (latency hides under staging) ----
  bool mA = false, mO = false;
  float msreg = 0.f;
  if (wv < 3) {
    int mbase = (wv * NB + b) * NNODES;
    mA = mask_at(mask, flag, mbase + 1 + ln);
    mO = mask_at(mask, flag, mbase + 65 + ln);
  } else if (ln >= 9 && ln < 12) {
    msreg = mask_at(mask, flag, ((ln - 9) * NB + b) * NNODES) ? 1.f : 0.f;
  }

  // ---- pass 0: stage h[b] (129x128 f32 -> bf16) into LDS; stage v2 ----
  const float4* h4 = (const float4*)(h + (size_t)b * NNODES * ND);
  for (int idx = tid; idx < NNODES * 32; idx += 256) {
    int r = idx >> 5, c4 = idx & 31;
    float4 v = h4[idx];
    uint2 p;
    p.x = pack2bf(v.x, v.y);
    p.y = pack2bf(v.z, v.w);
    *((uint2*)(hlu + r * ROWU + 2 * c4)) = p;
  }
  if (tid < 96) ((float4*)v2l)[tid] = ((const float4*)(ws + 1168))[tid];
  if (wv == 3 && ln >= 9 && ln < 12) msf[ln - 9] = msreg;
  __syncthreads();

  // ---- pass 1: attention logits ----
  if (wv < 3) {
    const int i = wv;                 // type index
    const int ra = 1 + ln;            // ally row
    const int ro = 65 + ln;           // opp row
    const uint4* hra = (const uint4*)(hlu + ra * ROWU);
    const uint4* hro = (const uint4*)(hlu + ro * ROWU);
    const float4* vv = (const float4*)(v2l + i * ND);
    float sa = 0.f, so = 0.f;
#pragma unroll 4
    for (int c = 0; c < 16; ++c) {
      uint4 xa = hra[c];
      uint4 xo = hro[c];
      float4 v0 = vv[2 * c], v1 = vv[2 * c + 1];
      float2 a0 = unpack2bf(xa.x), a1 = unpack2bf(xa.y), a2 = unpack2bf(xa.z), a3 = unpack2bf(xa.w);
      float2 o0 = unpack2bf(xo.x), o1 = unpack2bf(xo.y), o2 = unpack2bf(xo.z), o3 = unpack2bf(xo.w);
      sa += a0.x * v0.x + a0.y * v0.y + a1.x * v0.z + a1.y * v0.w
          + a2.x * v1.x + a2.y * v1.y + a3.x * v1.z + a3.y * v1.w;
      so += o0.x * v0.x + o0.y * v0.y + o1.x * v0.z + o1.y * v0.w
          + o2.x * v1.x + o2.y * v1.y + o3.x * v1.z + o3.y * v1.w;
    }
    ea[wv * 64 + ln] = mA ? -INFINITY : sa;
    eo[wv * 64 + ln] = mO ? -INFINITY : so;
  } else {
    if (ln < 9) {                     // e_self[j*3+i] = h_self . u[j,i]
      const float4* uu = (const float4*)(ws + 16 + (ln << 7));
      const uint4* hs = (const uint4*)(hlu);   // row 0
      float s = 0.f;
#pragma unroll 4
      for (int c = 0; c < 16; ++c) {
        uint4 x = hs[c];
        float4 u0 = uu[2 * c], u1 = uu[2 * c + 1];
        float2 f0 = unpack2bf(x.x), f1 = unpack2bf(x.y), f2 = unpack2bf(x.z), f3 = unpack2bf(x.w);
        s += f0.x * u0.x + f0.y * u0.y + f1.x * u0.z + f1.y * u0.w
           + f2.x * u1.x + f2.y * u1.y + f3.x * u1.z + f3.y * u1.w;
      }
      es[ln] = s;
    }
  }
  __syncthreads();

  // ---- pass 2: collapsed softmax (wave0 = ally, wave1 = opp) ----
  if (wv < 2) {
    float* e = (wv == 0) ? ea : eo;
    float* w = (wv == 0) ? wa : wo;
    float ms[3], S[3];
#pragma unroll
    for (int i = 0; i < 3; ++i) {
      float e0 = es[i], e1 = es[3 + i], e2 = es[6 + i];
      float m = fmaxf(fmaxf(e0, e1), e2);
      ms[i] = m;
      S[i] = expf(e0 - m) + expf(e1 - m) + expf(e2 - m);
    }
    float v0 = e[ln], v1 = e[64 + ln], v2v = e[128 + ln];
    float c0 = v0 + ms[0], c1 = v1 + ms[1], c2 = v2v + ms[2];
    float mx = fmaxf(fmaxf(c0, c1), c2);
    for (int off = 32; off; off >>= 1) mx = fmaxf(mx, __shfl_xor(mx, off));
    float t0 = 0.f, t1 = 0.f, t2 = 0.f;
    if (mx != -INFINITY) {
      t0 = (v0  == -INFINITY) ? 0.f : S[0] * expf(c0 - mx);
      t1 = (v1  == -INFINITY) ? 0.f : S[1] * expf(c1 - mx);
      t2 = (v2v == -INFINITY) ? 0.f : S[2] * expf(c2 - mx);
    }
    float z = t0 + t1 + t2;
    for (int off = 32; off; off >>= 1) z += __shfl_xor(z, off);
    float inv = (z > 0.f) ? 1.f / z : 0.f;
    w[ln] = t0 * inv; w[64 + ln] = t1 * inv; w[128 + ln] = t2 * inv;
  }
  __syncthreads();

  // ---- pass 3: g[t][d] = msf_t*h_self[d] + sum_n w[t,n]*h_node[n,d]  (wave = type) ----
  if (wv < 3) {
    const int l2 = ln;                       // owns d-pair (2*l2, 2*l2+1)
    float2 fs = unpack2bf(hlu[l2]);          // row 0
    float m = msf[wv];
    float a0 = m * fs.x, a1 = m * fs.y;
    const float* wap = wa + wv * 64;
    const float* wop = wo + wv * 64;
#pragma unroll 4
    for (int n = 0; n < 64; ++n) {
      float2 f = unpack2bf(hlu[(1 + n) * ROWU + l2]);
      float wgt = wap[n];
      a0 += wgt * f.x; a1 += wgt * f.y;
    }
#pragma unroll 4
    for (int n = 0; n < 64; ++n) {
      float2 f = unpack2bf(hlu[(65 + n) * ROWU + l2]);
      float wgt = wop[n];
      a0 += wgt * f.x; a1 += wgt * f.y;
    }
    gl[wv * ND + 2 * l2] = a0;
    gl[wv * ND + 2 * l2 + 1] = a1;
  }
  __syncthreads();

  // ---- pass 4: epilogue out[b,c] = elu( sum_t g[t] @ W[t][:,c] ) ----
  {
    int q = tid >> 6, c = tid & 63;
    float acc = 0.f;
#pragma unroll
    for (int t = 0; t < 3; ++t) {
      const float* gp = gl + t * ND;
      const float* Wp = W + t * 8192;
      for (int dd = 32 * q; dd < 32 * q + 32; ++dd) {
        acc += gp[dd] * Wp[dd * 64 + c];
      }
    }
    red[q * 64 + c] = acc;
  }
  __syncthreads();
  if (tid < 64) {
    float x = red[tid] + red[64 + tid] + red[128 + tid] + red[192 + tid];
    out[(size_t)b * NC + tid] = (x > 0.f) ? x : expm1f(x);
  }
}

extern "C" void kernel_launch(void* const* d_in, const int* in_sizes, int n_in,
                              void* d_out, int out_size, void* d_ws, size_t ws_size,
                              hipStream_t stream) {
  (void)in_sizes; (void)n_in; (void)out_size; (void)ws_size;
  const float* h   = (const float*)d_in[0];
  const float* W   = (const float*)d_in[1];
  const float* a   = (const float*)d_in[2];
  const void* mask = d_in[3];
  float* ws  = (float*)d_ws;
  float* out = (float*)d_out;

  hetgat_precomp<<<dim3(7), dim3(256), 0, stream>>>(W, a, mask, ws);
  hetgat_main<<<dim3(NB), dim3(256), 0, stream>>>(h, W, mask, ws, out);
}